// Round 1
// baseline (451.774 us; speedup 1.0000x reference)
//
#include <hip/hip_runtime.h>
#include <math.h>

#define NB 16
#define RB 64
#define HB 128
#define WB 128
#define DB 256

// ws layout (floats):
//   ex_m [NB*RB*WB]  : exp(lx - mlx)                  (map normalization, x-axis)
//   ey_m [NB*RB*HB]  : exp(ly - mly) * s              (s = e^m/(e^m+1e-12))
//   exT  [NB*WB*RB]  : transposed ex_m                (for coalesced GEMM staging)
//   eyT  [NB*HB*RB]  : transposed ey_m / (HB*WB)      (1/HW folded in)

__global__ void tables_kernel(const float* __restrict__ roi,
                              float* __restrict__ ws,
                              float* __restrict__ out_params) {
  const int nr = blockIdx.x;            // n*64 + r
  const int n  = nr >> 6;
  const int r  = nr & 63;
  const int t  = threadIdx.x;           // 0..127 (grid coordinate; HB==WB==128)

  const float mux = roi[nr * 4 + 0];
  const float muy = roi[nr * 4 + 1];
  const float sgx = roi[nr * 4 + 2];
  const float sgy = roi[nr * 4 + 3];

  const float g  = (t + 0.5f) * (1.0f / 128.0f);
  const float tx = fabsf(g - mux) / sgx;
  const float ty = fabsf(g - muy) / sgy;
  const float lx = -(tx * tx);          // BETA = 2.0
  const float ly = -(ty * ty);

  __shared__ float sdx[128], sdy[128];
  sdx[t] = lx; sdy[t] = ly;
  __syncthreads();
  for (int off = 64; off > 0; off >>= 1) {
    if (t < off) {
      sdx[t] = fmaxf(sdx[t], sdx[t + off]);
      sdy[t] = fmaxf(sdy[t], sdy[t + off]);
    }
    __syncthreads();
  }
  const float mlx = sdx[0], mly = sdy[0];

  const float em = expf(mlx + mly);             // == max over scores (separable)
  const float s  = em / (em + 1e-12f);
  const float exv = expf(lx - mlx);
  const float eyv = expf(ly - mly) * s;

  float* ex_m = ws;
  float* ey_m = ws + NB * RB * WB;
  float* exT  = ws + 2 * NB * RB * WB;
  float* eyT  = ws + 3 * NB * RB * WB;

  ex_m[nr * WB + t] = exv;
  ey_m[nr * HB + t] = eyv;
  exT[(n * WB + t) * RB + r] = exv;
  eyT[(n * HB + t) * RB + r] = eyv * (1.0f / (HB * WB));

  if (t < 4) out_params[nr * 4 + t] = roi[nr * 4 + t];
}

__global__ void map_kernel(const float* __restrict__ ws,
                           float* __restrict__ out_map) {
  const float* ex_m = ws;
  const float* ey_m = ws + NB * RB * WB;
  const int total = NB * RB * HB * WB / 4;      // float4 count
  for (int idx = blockIdx.x * blockDim.x + threadIdx.x; idx < total;
       idx += gridDim.x * blockDim.x) {
    const int w4 = idx & 31;                    // 32 float4 per row
    const int h  = (idx >> 5) & 127;
    const int nr = idx >> 12;
    const float  ey = ey_m[nr * HB + h];
    const float4 ex = *reinterpret_cast<const float4*>(ex_m + nr * WB + w4 * 4);
    float4 o;
    o.x = ey * ex.x; o.y = ey * ex.y; o.z = ey * ex.z; o.w = ey * ex.w;
    reinterpret_cast<float4*>(out_map)[idx] = o;
  }
}

// Block: (fc, n) with fc covering 2 h-rows. 256 threads = 4 waves.
// Wave wv handles rois [wv*16, wv*16+16); lane d4 owns d in [4*d4, 4*d4+4).
// Per h-row: build wrowT[w][r] = ey[r,h]*ex[r,w] in LDS, then stream the row of x
// (float4, fully coalesced: one wave's 64 lanes cover all 256 d of one pixel).
__global__ __launch_bounds__(256, 4) void feat_kernel(const float* __restrict__ x,
                                                      const float* __restrict__ ws,
                                                      float* __restrict__ out) {
  const float* exT = ws + 2 * NB * RB * WB;
  const float* eyT = ws + 3 * NB * RB * WB;
  const int n  = blockIdx.y;
  const int fc = blockIdx.x;            // 0..63 -> 2 rows each
  const int t  = threadIdx.x;
  const int d4 = t & 63;
  const int wv = t >> 6;
  const int r0 = wv * 16;

  __shared__ float wrowT[WB][RB];       // 32 KB

  float acc[16][4];
#pragma unroll
  for (int i = 0; i < 16; ++i)
#pragma unroll
    for (int j = 0; j < 4; ++j) acc[i][j] = 0.0f;

  for (int hh = 0; hh < 2; ++hh) {
    const int h = fc * 2 + hh;
    __syncthreads();
    const float* eyrow = eyT + (n * HB + h) * RB;   // 64 values (L1/L2 hot)
    const float* exn   = exT + n * WB * RB;         // [WB][RB]
    for (int i = t; i < WB * RB; i += 256) {
      wrowT[i >> 6][i & 63] = eyrow[i & 63] * exn[i];  // coalesced reads+stores
    }
    __syncthreads();

    const float* xrow = x + ((size_t)(n * HB + h) * WB) * DB + d4 * 4;
#pragma unroll 2
    for (int w = 0; w < WB; ++w) {
      const float4 xv = *reinterpret_cast<const float4*>(xrow + (size_t)w * DB);
#pragma unroll
      for (int rq = 0; rq < 4; ++rq) {
        // wave-uniform LDS address -> broadcast read, conflict-free
        const float4 wg = *reinterpret_cast<const float4*>(&wrowT[w][r0 + rq * 4]);
        float* a0 = acc[rq * 4 + 0];
        float* a1 = acc[rq * 4 + 1];
        float* a2 = acc[rq * 4 + 2];
        float* a3 = acc[rq * 4 + 3];
        a0[0] = fmaf(wg.x, xv.x, a0[0]); a0[1] = fmaf(wg.x, xv.y, a0[1]);
        a0[2] = fmaf(wg.x, xv.z, a0[2]); a0[3] = fmaf(wg.x, xv.w, a0[3]);
        a1[0] = fmaf(wg.y, xv.x, a1[0]); a1[1] = fmaf(wg.y, xv.y, a1[1]);
        a1[2] = fmaf(wg.y, xv.z, a1[2]); a1[3] = fmaf(wg.y, xv.w, a1[3]);
        a2[0] = fmaf(wg.z, xv.x, a2[0]); a2[1] = fmaf(wg.z, xv.y, a2[1]);
        a2[2] = fmaf(wg.z, xv.z, a2[2]); a2[3] = fmaf(wg.z, xv.w, a2[3]);
        a3[0] = fmaf(wg.w, xv.x, a3[0]); a3[1] = fmaf(wg.w, xv.y, a3[1]);
        a3[2] = fmaf(wg.w, xv.z, a3[2]); a3[3] = fmaf(wg.w, xv.w, a3[3]);
      }
    }
  }

#pragma unroll
  for (int i = 0; i < 16; ++i) {
    float* dst = out + ((size_t)(n * RB + r0 + i) * DB) + d4 * 4;
    atomicAdd(dst + 0, acc[i][0]);
    atomicAdd(dst + 1, acc[i][1]);
    atomicAdd(dst + 2, acc[i][2]);
    atomicAdd(dst + 3, acc[i][3]);
  }
}

extern "C" void kernel_launch(void* const* d_in, const int* in_sizes, int n_in,
                              void* d_out, int out_size, void* d_ws, size_t ws_size,
                              hipStream_t stream) {
  const float* x   = (const float*)d_in[0];
  const float* roi = (const float*)d_in[1];
  float* out        = (float*)d_out;
  float* ws         = (float*)d_ws;      // needs 4 * 131072 floats = 2 MB
  float* out_feat   = out;                         // 16*64*256
  float* out_params = out + NB * RB * DB;          // 16*64*4
  float* out_map    = out_params + NB * RB * 4;    // 16*64*128*128

  // features are accumulated with atomics -> zero them every call (deterministic)
  hipMemsetAsync(out_feat, 0, (size_t)NB * RB * DB * sizeof(float), stream);

  tables_kernel<<<NB * RB, 128, 0, stream>>>(roi, ws, out_params);
  map_kernel<<<2048, 256, 0, stream>>>(ws, out_map);
  feat_kernel<<<dim3(64, 16), 256, 0, stream>>>(x, ws, out_feat);
}

// Round 2
// 207.503 us; speedup vs baseline: 2.1772x; 2.1772x over previous
//
#include <hip/hip_runtime.h>
#include <hip/hip_bf16.h>
#include <math.h>

#define NB 16
#define RB 64
#define HB 128
#define WB 128
#define DB 256

typedef __attribute__((ext_vector_type(8))) short bf16x8;
typedef __attribute__((ext_vector_type(4))) float f32x4;

static __device__ __forceinline__ short f2bf(float f) {
  __hip_bfloat16 h = __float2bfloat16(f);
  return *reinterpret_cast<short*>(&h);
}

// ws layout (floats):
//   ex_m [NB*RB*WB]  : exp(lx - mlx)                  (x-axis table, no scale)
//   ey_m [NB*RB*HB]  : exp(ly - mly) * s              (map normalization path)
//   exT  [NB*WB*RB]  : transposed ex_m                (unused by feat now)
//   eyT  [NB*HB*RB]  : ey * s / (HB*WB)               (feat path, scales folded)

__global__ void tables_kernel(const float* __restrict__ roi,
                              float* __restrict__ ws,
                              float* __restrict__ out_params) {
  const int nr = blockIdx.x;            // n*64 + r
  const int n  = nr >> 6;
  const int r  = nr & 63;
  const int t  = threadIdx.x;           // 0..127

  const float mux = roi[nr * 4 + 0];
  const float muy = roi[nr * 4 + 1];
  const float sgx = roi[nr * 4 + 2];
  const float sgy = roi[nr * 4 + 3];

  const float g  = (t + 0.5f) * (1.0f / 128.0f);
  const float tx = fabsf(g - mux) / sgx;
  const float ty = fabsf(g - muy) / sgy;
  const float lx = -(tx * tx);          // BETA = 2.0
  const float ly = -(ty * ty);

  __shared__ float sdx[128], sdy[128];
  sdx[t] = lx; sdy[t] = ly;
  __syncthreads();
  for (int off = 64; off > 0; off >>= 1) {
    if (t < off) {
      sdx[t] = fmaxf(sdx[t], sdx[t + off]);
      sdy[t] = fmaxf(sdy[t], sdy[t + off]);
    }
    __syncthreads();
  }
  const float mlx = sdx[0], mly = sdy[0];

  const float em = expf(mlx + mly);             // == max over scores (separable)
  const float s  = em / (em + 1e-12f);
  const float exv = expf(lx - mlx);
  const float eyv = expf(ly - mly) * s;

  float* ex_m = ws;
  float* ey_m = ws + NB * RB * WB;
  float* exT  = ws + 2 * NB * RB * WB;
  float* eyT  = ws + 3 * NB * RB * WB;

  ex_m[nr * WB + t] = exv;
  ey_m[nr * HB + t] = eyv;
  exT[(n * WB + t) * RB + r] = exv;
  eyT[(n * HB + t) * RB + r] = eyv * (1.0f / (HB * WB));

  if (t < 4) out_params[nr * 4 + t] = roi[nr * 4 + t];
}

__global__ void map_kernel(const float* __restrict__ ws,
                           float* __restrict__ out_map) {
  const float* ex_m = ws;
  const float* ey_m = ws + NB * RB * WB;
  const int total = NB * RB * HB * WB / 4;      // float4 count
  for (int idx = blockIdx.x * blockDim.x + threadIdx.x; idx < total;
       idx += gridDim.x * blockDim.x) {
    const int w4 = idx & 31;                    // 32 float4 per row
    const int h  = (idx >> 5) & 127;
    const int nr = idx >> 12;
    const float  ey = ey_m[nr * HB + h];
    const float4 ex = *reinterpret_cast<const float4*>(ex_m + nr * WB + w4 * 4);
    float4 o;
    o.x = ey * ex.x; o.y = ey * ex.y; o.z = ey * ex.z; o.w = ey * ex.w;
    reinterpret_cast<float4*>(out_map)[idx] = o;
  }
}

// MFMA feature kernel. Grid: 512 blocks = (n:16) x (h-chunk:32, 4 rows each).
// 256 threads = 4 waves; wave wv owns d in [wv*64, wv*64+64).
// No LDS, no barriers: waves don't share x (disjoint d-slices).
// d->fragment interleave: fragment f, MFMA col nn -> d = wv*64 + nn*4 + f,
// so ONE coalesced float4 x-load per (lane, k) feeds all 4 d-fragments.
// A (the roi map) is rank-1: a[r,k=h*128+w] = eyT[n,h,r] * ex_m[n,r,w],
// generated in registers from L2-hot tables.
__global__ __launch_bounds__(256, 2) void feat_mfma_kernel(
    const float* __restrict__ x, const float* __restrict__ ws,
    float* __restrict__ out) {
  const float* ex_m = ws;                       // [NB*RB][WB]
  const float* eyT  = ws + 3 * NB * RB * WB;    // [NB*HB][RB]

  const int bid = blockIdx.x;
  const int n   = bid >> 5;
  const int h0  = (bid & 31) * 4;
  const int t   = threadIdx.x;
  const int l   = t & 63;
  const int wv  = t >> 6;
  const int l15 = l & 15;
  const int lk  = (l >> 4) * 8;        // this lane's k-offset within a k-step
  const int dbase = wv * 64 + l15 * 4; // x-load column

  f32x4 acc[4][4];
#pragma unroll
  for (int rf = 0; rf < 4; ++rf)
#pragma unroll
    for (int f = 0; f < 4; ++f) acc[rf][f] = (f32x4)0.0f;

  for (int h = h0; h < h0 + 4; ++h) {
    float eyv[4];
#pragma unroll
    for (int rf = 0; rf < 4; ++rf)
      eyv[rf] = eyT[(n * HB + h) * RB + rf * 16 + l15];

    const float* xrow = x + ((size_t)(n * HB + h) * WB) * DB;

#pragma unroll
    for (int ks = 0; ks < 4; ++ks) {
      const int wl = ks * 32 + lk;     // lane's first w for this k-step

      // ---- B fragments: 8 coalesced float4 x-loads, one per k ----
      f32x4 xv[8];
#pragma unroll
      for (int j = 0; j < 8; ++j)
        xv[j] = *reinterpret_cast<const f32x4*>(
            xrow + (size_t)(wl + j) * DB + dbase);

      // ---- A fragments: rank-1 weights from L2-hot tables ----
      bf16x8 afr[4];
#pragma unroll
      for (int rf = 0; rf < 4; ++rf) {
        const float* exr = ex_m + (size_t)(n * RB + rf * 16 + l15) * WB + wl;
        const f32x4 e0 = *reinterpret_cast<const f32x4*>(exr);
        const f32x4 e1 = *reinterpret_cast<const f32x4*>(exr + 4);
        bf16x8 a;
        a[0] = f2bf(eyv[rf] * e0.x); a[1] = f2bf(eyv[rf] * e0.y);
        a[2] = f2bf(eyv[rf] * e0.z); a[3] = f2bf(eyv[rf] * e0.w);
        a[4] = f2bf(eyv[rf] * e1.x); a[5] = f2bf(eyv[rf] * e1.y);
        a[6] = f2bf(eyv[rf] * e1.z); a[7] = f2bf(eyv[rf] * e1.w);
        afr[rf] = a;
      }

      bf16x8 bfr[4];
#pragma unroll
      for (int f = 0; f < 4; ++f) {
        bf16x8 b;
        b[0] = f2bf(xv[0][f]); b[1] = f2bf(xv[1][f]);
        b[2] = f2bf(xv[2][f]); b[3] = f2bf(xv[3][f]);
        b[4] = f2bf(xv[4][f]); b[5] = f2bf(xv[5][f]);
        b[6] = f2bf(xv[6][f]); b[7] = f2bf(xv[7][f]);
        bfr[f] = b;
      }

#pragma unroll
      for (int rf = 0; rf < 4; ++rf)
#pragma unroll
        for (int f = 0; f < 4; ++f)
          acc[rf][f] = __builtin_amdgcn_mfma_f32_16x16x32_bf16(
              afr[rf], bfr[f], acc[rf][f], 0, 0, 0);
    }
  }

  // D layout: col = lane&15, row = (lane>>4)*4 + reg (m89-verified).
#pragma unroll
  for (int rf = 0; rf < 4; ++rf) {
#pragma unroll
    for (int f = 0; f < 4; ++f) {
#pragma unroll
      for (int reg = 0; reg < 4; ++reg) {
        const int r = rf * 16 + (l >> 4) * 4 + reg;
        const int d = wv * 64 + l15 * 4 + f;
        atomicAdd(out + ((size_t)(n * RB + r)) * DB + d, acc[rf][f][reg]);
      }
    }
  }
}

extern "C" void kernel_launch(void* const* d_in, const int* in_sizes, int n_in,
                              void* d_out, int out_size, void* d_ws, size_t ws_size,
                              hipStream_t stream) {
  const float* x   = (const float*)d_in[0];
  const float* roi = (const float*)d_in[1];
  float* out        = (float*)d_out;
  float* ws         = (float*)d_ws;      // 4 * 131072 floats = 2 MB
  float* out_feat   = out;                         // 16*64*256
  float* out_params = out + NB * RB * DB;          // 16*64*4
  float* out_map    = out_params + NB * RB * 4;    // 16*64*128*128

  // features accumulate via atomics -> zero every call (deterministic)
  hipMemsetAsync(out_feat, 0, (size_t)NB * RB * DB * sizeof(float), stream);

  tables_kernel<<<NB * RB, 128, 0, stream>>>(roi, ws, out_params);
  map_kernel<<<2048, 256, 0, stream>>>(ws, out_map);
  feat_mfma_kernel<<<512, 256, 0, stream>>>(x, ws, out_feat);
}